// Round 10
// baseline (723.648 us; speedup 1.0000x reference)
//
#include <hip/hip_runtime.h>

#define T_LEN 2048
#define B_SZ  64
#define I_DIM 128
#define H_DIM 256

typedef _Float16 f16;
typedef _Float16 f16x8 __attribute__((ext_vector_type(8)));
typedef float    f32x4 __attribute__((ext_vector_type(4)));
typedef int      i32x4 __attribute__((ext_vector_type(4)));

// Raw barrier: orders LDS (lgkmcnt(0)) but leaves global prefetch loads in
// flight across the barrier (no vmcnt drain, unlike __syncthreads).
#define WG_BARRIER() do {                                  \
  asm volatile("s_waitcnt lgkmcnt(0)" ::: "memory");       \
  __builtin_amdgcn_s_barrier();                            \
  asm volatile("" ::: "memory");                           \
  __builtin_amdgcn_sched_barrier(0);                       \
} while (0)

// ---------------------------------------------------------------------------
// Kernel 1: xproj[t][b][:] = x[b][t][:] @ Wx + bias   (written into d_out)
// grid (16, 64): blockIdx.x = 128-t chunk, blockIdx.y = b. 256 thr = 4 waves.
// Wave w owns cols [64w, 64w+64).   (f16 MFMA is right here: M=16 tile full)
// ---------------------------------------------------------------------------
__global__ __launch_bounds__(256) void xproj_kernel(
    const float* __restrict__ x, const float* __restrict__ W,
    const float* __restrict__ bias, float* __restrict__ out) {
  const int b    = blockIdx.y;
  const int tc   = blockIdx.x * 128;
  const int w    = threadIdx.x >> 6;
  const int lane = threadIdx.x & 63;
  const int cl   = lane & 15;
  const int kh   = lane >> 4;

  // Wx fragments: B[k][c], c = 64w+16g+cl, k = 32q+8kh+j (8 consecutive k/lane)
  f16x8 Bf[4][4];
#pragma unroll
  for (int g = 0; g < 4; ++g) {
    const int c = 64 * w + 16 * g + cl;
#pragma unroll
    for (int q = 0; q < 4; ++q)
#pragma unroll
      for (int j = 0; j < 8; ++j)
        Bf[g][q][j] = (f16)W[(32 * q + 8 * kh + j) * H_DIM + c];
  }
  float bv[4];
#pragma unroll
  for (int g = 0; g < 4; ++g) bv[g] = bias[64 * w + 16 * g + cl];

#pragma unroll 1
  for (int tb = 0; tb < 128; tb += 16) {
    const int t0 = tc + tb;
    // A fragments: A[r][k] = x[b][t0+r][k], r = cl, k = 8kh+j+32q
    const float* xrow = x + ((size_t)b * T_LEN + (t0 + cl)) * I_DIM + 8 * kh;
    f16x8 Af[4];
#pragma unroll
    for (int q = 0; q < 4; ++q) {
      float4 u0 = *(const float4*)(xrow + 32 * q);
      float4 u1 = *(const float4*)(xrow + 32 * q + 4);
      f16x8 a;
      a[0] = (f16)u0.x; a[1] = (f16)u0.y; a[2] = (f16)u0.z; a[3] = (f16)u0.w;
      a[4] = (f16)u1.x; a[5] = (f16)u1.y; a[6] = (f16)u1.z; a[7] = (f16)u1.w;
      Af[q] = a;
    }
#pragma unroll
    for (int g = 0; g < 4; ++g) {
      f32x4 acc = {0.f, 0.f, 0.f, 0.f};
#pragma unroll
      for (int q = 0; q < 4; ++q)
        acc = __builtin_amdgcn_mfma_f32_16x16x32_f16(Af[q], Bf[g][q], acc, 0, 0, 0);
      // D: row = 4kh+j, col = cl (+16g+64w)
#pragma unroll
      for (int j = 0; j < 4; ++j) {
        const int t = t0 + 4 * kh + j;
        out[((size_t)t * B_SZ + b) * H_DIM + 64 * w + 16 * g + cl] = acc[j] + bv[g];
      }
    }
  }
}

// ---------------------------------------------------------------------------
// Kernel 2: sequential scan — i8 MFMA, 16 INDEPENDENT accumulators.
//
// r9 post-mortem: with 4 chains x 4-deep, a lone wave has only 4 independent
// MFMAs in flight; if MFMA result latency L > 4 issue slots (~82 cyc) the
// wave stalls between dependency groups (step ~ 4L, matches measured 762).
// Fix: 16 separate accumulators (all 16 MFMAs independent, pure-throughput
// issue = 326 cyc + one L at the end), reduced by a v_add tree afterwards.
// Sigmoid spine shortened: cc = -log2e*(zoff+xp) is precomputed at PREFETCH
// time (off the spine), so the critical chain is cvt -> fma -> v_exp_f32 ->
// add 1 -> rcp -> quant-fma -> rndne -> cvt -> ds_write_b8.
//
// Structure = r7 (best measured): 4 waves (1/SIMD), wave w owns cols
// [64w,64w+64) via 4 B-tiles sharing ONE multi-row A fragment set (h in
// A-rows {0,4,8,12}, reader lanes cl in {0,4,8,12} -> 4 guarded broadcast
// ds_read_b128 per wave per step). Lane l's z picked with 3 cndmasks.
// Own-chunk pre-read/counted-lgkm dropped (proven null r8); plain barrier.
//
// Fixed-point encoding (absmax floor-equal to f16, verified r7):
//   hq = round(h*254) - 127 ; wq = round(Wh*2490)
//   z  = idot/(254*2490) + zoff + xp,  zoff = 127*colsum/(254*2490)
// ---------------------------------------------------------------------------
#define MFMAI8(A, B, C) __builtin_amdgcn_mfma_i32_16x16x64_i8((A), (B), (C), 0, 0, 0)

#define SW_SCALE 2490.0f
#define INVS (1.0f / (254.0f * SW_SCALE))
#define NLOG2E (-1.4426950408889634f)
#define RS (B_SZ * H_DIM)

#define RNN_STEP(cc, RB) do {                                                \
  if (rdlane) {                                                              \
    Aq0 = *(const i32x4*)&hbuf8[RB][rd0];                                    \
    Aq1 = *(const i32x4*)&hbuf8[RB][rd1];                                    \
    Aq2 = *(const i32x4*)&hbuf8[RB][rd2];                                    \
    Aq3 = *(const i32x4*)&hbuf8[RB][rd3];                                    \
  }                                                                          \
  i32x4 a00 = MFMAI8(Aq0, Bq[0][0], Zacc);                                   \
  i32x4 a10 = MFMAI8(Aq0, Bq[1][0], Zacc);                                   \
  i32x4 a20 = MFMAI8(Aq0, Bq[2][0], Zacc);                                   \
  i32x4 a30 = MFMAI8(Aq0, Bq[3][0], Zacc);                                   \
  i32x4 a01 = MFMAI8(Aq1, Bq[0][1], Zacc);                                   \
  i32x4 a11 = MFMAI8(Aq1, Bq[1][1], Zacc);                                   \
  i32x4 a21 = MFMAI8(Aq1, Bq[2][1], Zacc);                                   \
  i32x4 a31 = MFMAI8(Aq1, Bq[3][1], Zacc);                                   \
  i32x4 a02 = MFMAI8(Aq2, Bq[0][2], Zacc);                                   \
  i32x4 a12 = MFMAI8(Aq2, Bq[1][2], Zacc);                                   \
  i32x4 a22 = MFMAI8(Aq2, Bq[2][2], Zacc);                                   \
  i32x4 a32 = MFMAI8(Aq2, Bq[3][2], Zacc);                                   \
  i32x4 a03 = MFMAI8(Aq3, Bq[0][3], Zacc);                                   \
  i32x4 a13 = MFMAI8(Aq3, Bq[1][3], Zacc);                                   \
  i32x4 a23 = MFMAI8(Aq3, Bq[2][3], Zacc);                                   \
  i32x4 a33 = MFMAI8(Aq3, Bq[3][3], Zacc);                                   \
  int i0 = (a00[0] + a01[0]) + (a02[0] + a03[0]);                            \
  int i1 = (a10[0] + a11[0]) + (a12[0] + a13[0]);                            \
  int i2 = (a20[0] + a21[0]) + (a22[0] + a23[0]);                            \
  int i3 = (a30[0] + a31[0]) + (a32[0] + a33[0]);                            \
  int idot = g1 ? i1 : i0;                                                   \
  idot = g2 ? i2 : idot;                                                     \
  idot = g3 ? i3 : idot;                                                     \
  float arg = __builtin_fmaf((float)idot, K1, (cc));                         \
  float ex;                                                                  \
  asm("v_exp_f32 %0, %1" : "=v"(ex) : "v"(arg));                             \
  float hh = __builtin_amdgcn_rcpf(1.0f + ex);                               \
  int hq = (int)__builtin_rintf(__builtin_fmaf(hh, 254.0f, -127.0f));        \
  hbuf8[(RB) ^ 1][tid] = (signed char)hq;                                    \
  WG_BARRIER();                                                              \
  *opSt = hh; opSt += RS;                                                    \
} while (0)

__global__ __launch_bounds__(256, 1) void rnn_kernel(
    const float* __restrict__ W, float* out) {
  const int b    = blockIdx.x;
  const int tid  = threadIdx.x;
  const int w    = tid >> 6;
  const int lane = tid & 63;
  const int cl   = lane & 15;
  const int kh   = lane >> 4;

  __shared__ __align__(16) signed char hbuf8[2][H_DIM];
  // h0 = 0  ->  hq = round(0*254) - 127 = -127
  hbuf8[0][tid] = (signed char)-127;
  hbuf8[1][tid] = (signed char)-127;

  // Quantized Wh fragments: tile g, K-chunk q: c = 64w+16g+cl,
  // k = 64q + 16kh + 4d + j. 4 tiles x 4 q x 4 VGPR = 64 VGPRs.
  i32x4 Bq[4][4];
#pragma unroll
  for (int g = 0; g < 4; ++g) {
    const int c = 64 * w + 16 * g + cl;
#pragma unroll
    for (int q = 0; q < 4; ++q) {
#pragma unroll
      for (int d = 0; d < 4; ++d) {
        int dw = 0;
#pragma unroll
        for (int j = 0; j < 4; ++j) {
          const int k = 64 * q + 16 * kh + 4 * d + j;
          const int qv = (int)__builtin_rintf(W[(I_DIM + k) * H_DIM + c] * SW_SCALE);
          dw |= (qv & 0xff) << (8 * j);
        }
        Bq[g][q][d] = dw;
      }
    }
  }

  // Per-thread column constant: zoff = 127 * colsum(c=tid) * INVS.
  int cs = 0;
#pragma unroll 4
  for (int k = 0; k < H_DIM; ++k)
    cs += (int)__builtin_rintf(W[(I_DIM + k) * H_DIM + tid] * SW_SCALE);
  const float zoff = 127.0f * (float)cs * INVS;
  const float K1 = INVS * NLOG2E;    // folds /(254*2490) and *-log2(e)

  // A fragments: rows {0,4,8,12} carry hq (reader lanes cl in {0,4,8,12});
  // all other rows stay zero forever.
  i32x4 Aq0 = {0, 0, 0, 0}, Aq1 = {0, 0, 0, 0};
  i32x4 Aq2 = {0, 0, 0, 0}, Aq3 = {0, 0, 0, 0};
  const i32x4 Zacc = {0, 0, 0, 0};

  const bool rdlane = ((cl & 3) == 0);
  const int  rd0 = 0   + 16 * kh;
  const int  rd1 = 64  + 16 * kh;
  const int  rd2 = 128 + 16 * kh;
  const int  rd3 = 192 + 16 * kh;

  // z-selection masks: lane group picks its tile's accumulator.
  const bool g1 = (lane >> 4) == 1;
  const bool g2 = (lane >> 4) == 2;
  const bool g3 = (lane >> 4) == 3;

  float* op   = out + (size_t)b * H_DIM + tid;   // &out[(t*B+b)*H+tid], t=0
  float* opSt = op;
  const float* opPre = op + 4 * (size_t)RS;

  __syncthreads();

  // xp prefetch pipeline, depth 4; cc = -log2e*(zoff+xp) computed at
  // prefetch time so only one fma sits on the critical spine.
  float c0 = NLOG2E * (zoff + op[0 * (size_t)RS]);
  float c1 = NLOG2E * (zoff + op[1 * (size_t)RS]);
  float c2 = NLOG2E * (zoff + op[2 * (size_t)RS]);
  float c3 = NLOG2E * (zoff + op[3 * (size_t)RS]);

  // main loop: t = 0..2043 (511 x 4 steps), prefetch rows t+4..t+7
#pragma unroll 1
  for (int it = 0; it < (T_LEN - 4) / 4; ++it) {
    float n0 = opPre[0 * (size_t)RS];
    RNN_STEP(c0, 0); c0 = NLOG2E * (zoff + n0);
    float n1 = opPre[1 * (size_t)RS];
    RNN_STEP(c1, 1); c1 = NLOG2E * (zoff + n1);
    float n2 = opPre[2 * (size_t)RS];
    RNN_STEP(c2, 0); c2 = NLOG2E * (zoff + n2);
    float n3 = opPre[3 * (size_t)RS];
    RNN_STEP(c3, 1); c3 = NLOG2E * (zoff + n3);
    opPre += 4 * (size_t)RS;
  }
  // epilogue: t = 2044..2047, no prefetch
  RNN_STEP(c0, 0);
  RNN_STEP(c1, 1);
  RNN_STEP(c2, 0);
  RNN_STEP(c3, 1);
}

extern "C" void kernel_launch(void* const* d_in, const int* in_sizes, int n_in,
                              void* d_out, int out_size, void* d_ws, size_t ws_size,
                              hipStream_t stream) {
  (void)in_sizes; (void)n_in; (void)d_ws; (void)ws_size; (void)out_size;
  const float* x    = (const float*)d_in[0];
  const float* W    = (const float*)d_in[1];
  const float* bias = (const float*)d_in[2];
  float* out = (float*)d_out;

  xproj_kernel<<<dim3(16, 64), 256, 0, stream>>>(x, W, bias, out);
  rnn_kernel<<<64, 256, 0, stream>>>(W, out);
}

// Round 11
// 637.423 us; speedup vs baseline: 1.1353x; 1.1353x over previous
//
#include <hip/hip_runtime.h>

#define T_LEN 2048
#define B_SZ  64
#define I_DIM 128
#define H_DIM 256

typedef _Float16 f16;
typedef _Float16 f16x8 __attribute__((ext_vector_type(8)));
typedef float    f32x4 __attribute__((ext_vector_type(4)));
typedef int      i32x4 __attribute__((ext_vector_type(4)));

// Raw barrier: orders LDS (lgkmcnt(0)) but leaves global prefetch loads in
// flight across the barrier (no vmcnt drain, unlike __syncthreads).
#define WG_BARRIER() do {                                  \
  asm volatile("s_waitcnt lgkmcnt(0)" ::: "memory");       \
  __builtin_amdgcn_s_barrier();                            \
  asm volatile("" ::: "memory");                           \
  __builtin_amdgcn_sched_barrier(0);                       \
} while (0)

// ---------------------------------------------------------------------------
// Kernel 1: xproj[t][b][:] = x[b][t][:] @ Wx + bias   (written into d_out)
// grid (16, 64): blockIdx.x = 128-t chunk, blockIdx.y = b. 256 thr = 4 waves.
// Wave w owns cols [64w, 64w+64).   (f16 MFMA is right here: M=16 tile full)
// ---------------------------------------------------------------------------
__global__ __launch_bounds__(256) void xproj_kernel(
    const float* __restrict__ x, const float* __restrict__ W,
    const float* __restrict__ bias, float* __restrict__ out) {
  const int b    = blockIdx.y;
  const int tc   = blockIdx.x * 128;
  const int w    = threadIdx.x >> 6;
  const int lane = threadIdx.x & 63;
  const int cl   = lane & 15;
  const int kh   = lane >> 4;

  // Wx fragments: B[k][c], c = 64w+16g+cl, k = 32q+8kh+j (8 consecutive k/lane)
  f16x8 Bf[4][4];
#pragma unroll
  for (int g = 0; g < 4; ++g) {
    const int c = 64 * w + 16 * g + cl;
#pragma unroll
    for (int q = 0; q < 4; ++q)
#pragma unroll
      for (int j = 0; j < 8; ++j)
        Bf[g][q][j] = (f16)W[(32 * q + 8 * kh + j) * H_DIM + c];
  }
  float bv[4];
#pragma unroll
  for (int g = 0; g < 4; ++g) bv[g] = bias[64 * w + 16 * g + cl];

#pragma unroll 1
  for (int tb = 0; tb < 128; tb += 16) {
    const int t0 = tc + tb;
    // A fragments: A[r][k] = x[b][t0+r][k], r = cl, k = 8kh+j+32q
    const float* xrow = x + ((size_t)b * T_LEN + (t0 + cl)) * I_DIM + 8 * kh;
    f16x8 Af[4];
#pragma unroll
    for (int q = 0; q < 4; ++q) {
      float4 u0 = *(const float4*)(xrow + 32 * q);
      float4 u1 = *(const float4*)(xrow + 32 * q + 4);
      f16x8 a;
      a[0] = (f16)u0.x; a[1] = (f16)u0.y; a[2] = (f16)u0.z; a[3] = (f16)u0.w;
      a[4] = (f16)u1.x; a[5] = (f16)u1.y; a[6] = (f16)u1.z; a[7] = (f16)u1.w;
      Af[q] = a;
    }
#pragma unroll
    for (int g = 0; g < 4; ++g) {
      f32x4 acc = {0.f, 0.f, 0.f, 0.f};
#pragma unroll
      for (int q = 0; q < 4; ++q)
        acc = __builtin_amdgcn_mfma_f32_16x16x32_f16(Af[q], Bf[g][q], acc, 0, 0, 0);
      // D: row = 4kh+j, col = cl (+16g+64w)
#pragma unroll
      for (int j = 0; j < 4; ++j) {
        const int t = t0 + 4 * kh + j;
        out[((size_t)t * B_SZ + b) * H_DIM + 64 * w + 16 * g + cl] = acc[j] + bv[g];
      }
    }
  }
}

// ---------------------------------------------------------------------------
// Kernel 2: sequential scan — i8 MFMA (PROVEN-BEST r7 structure, 650 µs).
//
// r8/r9/r10 post-mortems: own-chunk read overlap, 2-waves/SIMD tail overlap,
// and 16-independent-accumulator ILP were all null-to-NEGATIVE. Converged
// model: step = 16 MFMA issue (326 cyc/SIMD) + ~450-cyc serial spine
// (h-write -> barrier -> ds_read -> MFMA drain -> select -> sigmoid ->
// quant), every element on the recurrence's dependency chain — nothing to
// overlap within a chain; co-locating chains only adds pipe contention;
// cross-CU exchange and sub-i8 dtypes are dead (cost/precision arithmetic
// in r2/r6/r10 notes). This round: r7 verbatim + ONE spine shave — fold
// /(254*2490), *-log2(e), zoff+xp into a single fma with cc precomputed at
// prefetch time (off-spine), and call v_exp_f32 directly.
//
// Structure: 4 waves (1/SIMD), wave w owns cols [64w,64w+64) via 4 B-tiles
// sharing ONE multi-row A fragment set (h in A-rows {0,4,8,12}, reader
// lanes cl in {0,4,8,12} -> 4 guarded broadcast ds_read_b128 per wave).
// 4 accumulator chains x 4-deep; lane l's z picked with 3 cndmasks.
//
// Fixed-point encoding (absmax floor-equal to f16, verified r7):
//   hq = round(h*254) - 127 ; wq = round(Wh*2490)
//   z  = idot/(254*2490) + zoff + xp,  zoff = 127*colsum/(254*2490)
// ---------------------------------------------------------------------------
#define MFMAI8(A, B, C) __builtin_amdgcn_mfma_i32_16x16x64_i8((A), (B), (C), 0, 0, 0)

#define SW_SCALE 2490.0f
#define INVS (1.0f / (254.0f * SW_SCALE))
#define NLOG2E (-1.4426950408889634f)
#define RS (B_SZ * H_DIM)

#define RNN_STEP(cc, RB) do {                                                \
  if (rdlane) {                                                              \
    Aq0 = *(const i32x4*)&hbuf8[RB][rd0];                                    \
    Aq1 = *(const i32x4*)&hbuf8[RB][rd1];                                    \
    Aq2 = *(const i32x4*)&hbuf8[RB][rd2];                                    \
    Aq3 = *(const i32x4*)&hbuf8[RB][rd3];                                    \
  }                                                                          \
  i32x4 a0 = MFMAI8(Aq0, Bq[0][0], Zacc);                                    \
  i32x4 a1 = MFMAI8(Aq0, Bq[1][0], Zacc);                                    \
  i32x4 a2 = MFMAI8(Aq0, Bq[2][0], Zacc);                                    \
  i32x4 a3 = MFMAI8(Aq0, Bq[3][0], Zacc);                                    \
  a0 = MFMAI8(Aq1, Bq[0][1], a0);                                            \
  a1 = MFMAI8(Aq1, Bq[1][1], a1);                                            \
  a2 = MFMAI8(Aq1, Bq[2][1], a2);                                            \
  a3 = MFMAI8(Aq1, Bq[3][1], a3);                                            \
  a0 = MFMAI8(Aq2, Bq[0][2], a0);                                            \
  a1 = MFMAI8(Aq2, Bq[1][2], a1);                                            \
  a2 = MFMAI8(Aq2, Bq[2][2], a2);                                            \
  a3 = MFMAI8(Aq2, Bq[3][2], a3);                                            \
  a0 = MFMAI8(Aq3, Bq[0][3], a0);                                            \
  a1 = MFMAI8(Aq3, Bq[1][3], a1);                                            \
  a2 = MFMAI8(Aq3, Bq[2][3], a2);                                            \
  a3 = MFMAI8(Aq3, Bq[3][3], a3);                                            \
  int idot = g1 ? a1[0] : a0[0];                                             \
  idot = g2 ? a2[0] : idot;                                                  \
  idot = g3 ? a3[0] : idot;                                                  \
  float arg = __builtin_fmaf((float)idot, K1, (cc));                         \
  float ex;                                                                  \
  asm("v_exp_f32 %0, %1" : "=v"(ex) : "v"(arg));                             \
  float hh = __builtin_amdgcn_rcpf(1.0f + ex);                               \
  int hq = (int)__builtin_rintf(__builtin_fmaf(hh, 254.0f, -127.0f));        \
  hbuf8[(RB) ^ 1][tid] = (signed char)hq;                                    \
  WG_BARRIER();                                                              \
  *opSt = hh; opSt += RS;                                                    \
} while (0)

__global__ __launch_bounds__(256, 1) void rnn_kernel(
    const float* __restrict__ W, float* out) {
  const int b    = blockIdx.x;
  const int tid  = threadIdx.x;
  const int w    = tid >> 6;
  const int lane = tid & 63;
  const int cl   = lane & 15;
  const int kh   = lane >> 4;

  __shared__ __align__(16) signed char hbuf8[2][H_DIM];
  // h0 = 0  ->  hq = round(0*254) - 127 = -127
  hbuf8[0][tid] = (signed char)-127;
  hbuf8[1][tid] = (signed char)-127;

  // Quantized Wh fragments: tile g, K-chunk q: c = 64w+16g+cl,
  // k = 64q + 16kh + 4d + j. 4 tiles x 4 q x 4 VGPR = 64 VGPRs.
  i32x4 Bq[4][4];
#pragma unroll
  for (int g = 0; g < 4; ++g) {
    const int c = 64 * w + 16 * g + cl;
#pragma unroll
    for (int q = 0; q < 4; ++q) {
#pragma unroll
      for (int d = 0; d < 4; ++d) {
        int dw = 0;
#pragma unroll
        for (int j = 0; j < 4; ++j) {
          const int k = 64 * q + 16 * kh + 4 * d + j;
          const int qv = (int)__builtin_rintf(W[(I_DIM + k) * H_DIM + c] * SW_SCALE);
          dw |= (qv & 0xff) << (8 * j);
        }
        Bq[g][q][d] = dw;
      }
    }
  }

  // Per-thread column constant: zoff = 127 * colsum(c=tid) * INVS.
  int cs = 0;
#pragma unroll 4
  for (int k = 0; k < H_DIM; ++k)
    cs += (int)__builtin_rintf(W[(I_DIM + k) * H_DIM + tid] * SW_SCALE);
  const float zoff = 127.0f * (float)cs * INVS;
  const float K1 = INVS * NLOG2E;    // folds /(254*2490) and *-log2(e)

  // A fragments: rows {0,4,8,12} carry hq (reader lanes cl in {0,4,8,12});
  // all other rows stay zero forever.
  i32x4 Aq0 = {0, 0, 0, 0}, Aq1 = {0, 0, 0, 0};
  i32x4 Aq2 = {0, 0, 0, 0}, Aq3 = {0, 0, 0, 0};
  const i32x4 Zacc = {0, 0, 0, 0};

  const bool rdlane = ((cl & 3) == 0);
  const int  rd0 = 0   + 16 * kh;
  const int  rd1 = 64  + 16 * kh;
  const int  rd2 = 128 + 16 * kh;
  const int  rd3 = 192 + 16 * kh;

  // z-selection masks: lane group picks its tile's accumulator.
  const bool g1 = (lane >> 4) == 1;
  const bool g2 = (lane >> 4) == 2;
  const bool g3 = (lane >> 4) == 3;

  float* op   = out + (size_t)b * H_DIM + tid;   // &out[(t*B+b)*H+tid], t=0
  float* opSt = op;
  const float* opPre = op + 4 * (size_t)RS;

  __syncthreads();

  // xp prefetch pipeline, depth 4; cc = -log2e*(zoff+xp) computed at
  // prefetch time so only one fma sits on the critical spine.
  float c0 = NLOG2E * (zoff + op[0 * (size_t)RS]);
  float c1 = NLOG2E * (zoff + op[1 * (size_t)RS]);
  float c2 = NLOG2E * (zoff + op[2 * (size_t)RS]);
  float c3 = NLOG2E * (zoff + op[3 * (size_t)RS]);

  // main loop: t = 0..2043 (511 x 4 steps), prefetch rows t+4..t+7
#pragma unroll 1
  for (int it = 0; it < (T_LEN - 4) / 4; ++it) {
    float n0 = opPre[0 * (size_t)RS];
    RNN_STEP(c0, 0); c0 = NLOG2E * (zoff + n0);
    float n1 = opPre[1 * (size_t)RS];
    RNN_STEP(c1, 1); c1 = NLOG2E * (zoff + n1);
    float n2 = opPre[2 * (size_t)RS];
    RNN_STEP(c2, 0); c2 = NLOG2E * (zoff + n2);
    float n3 = opPre[3 * (size_t)RS];
    RNN_STEP(c3, 1); c3 = NLOG2E * (zoff + n3);
    opPre += 4 * (size_t)RS;
  }
  // epilogue: t = 2044..2047, no prefetch
  RNN_STEP(c0, 0);
  RNN_STEP(c1, 1);
  RNN_STEP(c2, 0);
  RNN_STEP(c3, 1);
}

extern "C" void kernel_launch(void* const* d_in, const int* in_sizes, int n_in,
                              void* d_out, int out_size, void* d_ws, size_t ws_size,
                              hipStream_t stream) {
  (void)in_sizes; (void)n_in; (void)d_ws; (void)ws_size; (void)out_size;
  const float* x    = (const float*)d_in[0];
  const float* W    = (const float*)d_in[1];
  const float* bias = (const float*)d_in[2];
  float* out = (float*)d_out;

  xproj_kernel<<<dim3(16, 64), 256, 0, stream>>>(x, W, bias, out);
  rnn_kernel<<<64, 256, 0, stream>>>(W, out);
}